// Round 8
// baseline (6437.758 us; speedup 1.0000x reference)
//
#include <hip/hip_runtime.h>

#define T_LEN  4096
#define CHUNK  32
#define MLP_HID 40
#define HP     68    // h_hist row pitch (floats)
#define HTP    34    // h_T row pitch
#define W1P    68    // W1 LDS row pitch
#define RP     9     // red_lds pitch

typedef float v2f __attribute__((ext_vector_type(2)));
typedef float v4f __attribute__((ext_vector_type(4)));

#define LO2(x) __builtin_shufflevector(x, x, 0, 1)
#define HI2(x) __builtin_shufflevector(x, x, 2, 3)

// ---- VOP3P packed fp32, op_sel broadcasts; ALL operands are v2f pairs ----
__device__ __forceinline__ v2f pk_mul_lo(v2f h, v2f w) {   // both halves use h.lo
    v2f d;
    asm("v_pk_mul_f32 %0, %1, %2 op_sel:[0,0] op_sel_hi:[0,1]"
        : "=v"(d) : "v"(h), "v"(w));
    return d;
}
__device__ __forceinline__ v2f pk_mul_hi(v2f h, v2f w) {   // both halves use h.hi
    v2f d;
    asm("v_pk_mul_f32 %0, %1, %2 op_sel:[1,0] op_sel_hi:[1,1]"
        : "=v"(d) : "v"(h), "v"(w));
    return d;
}
__device__ __forceinline__ v2f pk_fma_lo(v2f h, v2f w, v2f c) {
    v2f d;
    asm("v_pk_fma_f32 %0, %1, %2, %3 op_sel:[0,0,0] op_sel_hi:[0,1,1]"
        : "=v"(d) : "v"(h), "v"(w), "v"(c));
    return d;
}
__device__ __forceinline__ v2f pk_fma_hi(v2f h, v2f w, v2f c) {
    v2f d;
    asm("v_pk_fma_f32 %0, %1, %2, %3 op_sel:[1,0,0] op_sel_hi:[1,1,1]"
        : "=v"(d) : "v"(h), "v"(w), "v"(c));
    return d;
}
// weight broadcast: both halves use w.lo / w.hi (w is a v2f PAIR — reg-pair legal)
__device__ __forceinline__ v2f pk_fma_wlo(v2f h, v2f w, v2f c) {
    v2f d;
    asm("v_pk_fma_f32 %0, %1, %2, %3 op_sel:[0,0,0] op_sel_hi:[1,0,1]"
        : "=v"(d) : "v"(h), "v"(w), "v"(c));
    return d;
}
__device__ __forceinline__ v2f pk_fma_whi(v2f h, v2f w, v2f c) {
    v2f d;
    asm("v_pk_fma_f32 %0, %1, %2, %3 op_sel:[0,1,0] op_sel_hi:[1,1,1]"
        : "=v"(d) : "v"(h), "v"(w), "v"(c));
    return d;
}
__device__ __forceinline__ v2f pk_fma(v2f a, v2f b, v2f c) {
    v2f d;
    asm("v_pk_fma_f32 %0, %1, %2, %3" : "=v"(d) : "v"(a), "v"(b), "v"(c));
    return d;
}
__device__ __forceinline__ v2f pk_add(v2f a, v2f b) {
    v2f d;
    asm("v_pk_add_f32 %0, %1, %2" : "=v"(d) : "v"(a), "v"(b));
    return d;
}

__device__ __forceinline__ float fast_sigmoid(float x) {
    float e = __builtin_amdgcn_exp2f(x * -1.4426950408889634f);
    return __builtin_amdgcn_rcpf(1.0f + e);
}
__device__ __forceinline__ float fast_tanh(float x) {
    float e = __builtin_amdgcn_exp2f(x * 2.8853900817779268f);
    return 1.0f - 2.0f * __builtin_amdgcn_rcpf(1.0f + e);
}

__global__ __launch_bounds__(64, 1)
void lstm_mlp_kernel(const float* __restrict__ inputs,
                     const float* __restrict__ W_ih,
                     const float* __restrict__ W_hh,
                     const float* __restrict__ b_ih,
                     const float* __restrict__ b_hh,
                     const float* __restrict__ W1,
                     const float* __restrict__ b1,
                     const float* __restrict__ W2,
                     const float* __restrict__ b2,
                     float* __restrict__ out)
{
    __shared__ __align__(16) float x_lds[T_LEN];           // 16 KB input row
    __shared__ __align__(16) float h_hist[CHUNK * HP];     // t-major h rows
    __shared__ __align__(16) float h_T[64 * HTP];          // u-major transposed copy
    __shared__ __align__(16) float w1_lds[MLP_HID * W1P];
    __shared__ float b1_lds[MLP_HID];
    __shared__ float w2_lds[MLP_HID];
    __shared__ float red_lds[CHUNK * RP];

    const int u = threadIdx.x;        // lane = hidden unit (64 lanes, 1 wave)
    const int b = blockIdx.x;

    // ---- prologue: stage x row ----
    const float4* in4 = (const float4*)(inputs + (size_t)b * T_LEN);
    float4* x4 = (float4*)x_lds;
    #pragma unroll
    for (int r = 0; r < 16; ++r) x4[u + 64 * r] = in4[u + 64 * r];

    // W_hh rows i,f,g,o of unit u packed as {i,f} / {g,o} per-k pairs
    v2f wIF[64], wGO[64];
    {
        const v4f* pI = (const v4f*)(W_hh + (0 * 64 + u) * 64);
        const v4f* pF = (const v4f*)(W_hh + (1 * 64 + u) * 64);
        const v4f* pG = (const v4f*)(W_hh + (2 * 64 + u) * 64);
        const v4f* pO = (const v4f*)(W_hh + (3 * 64 + u) * 64);
        #pragma unroll
        for (int m = 0; m < 16; ++m) {
            v4f vi = pI[m], vf = pF[m], vg = pG[m], vo = pO[m];
            #pragma unroll
            for (int e = 0; e < 4; ++e) {
                wIF[4 * m + e] = (v2f){vi[e], vf[e]};
                wGO[4 * m + e] = (v2f){vg[e], vo[e]};
            }
        }
    }
    const v2f wihIF  = (v2f){W_ih[u],           W_ih[64 + u]};
    const v2f wihGO  = (v2f){W_ih[128 + u],     W_ih[192 + u]};
    const v2f biasIF = (v2f){b_ih[u] + b_hh[u], b_ih[64 + u] + b_hh[64 + u]};
    const v2f biasGO = (v2f){b_ih[128 + u] + b_hh[128 + u],
                             b_ih[192 + u] + b_hh[192 + u]};
    const float b2v = b2[0];

    for (int p = u; p < MLP_HID * 65; p += 64) {
        int row = p / 65, col = p - row * 65;
        w1_lds[row * W1P + col] = W1[p];
    }
    if (u < MLP_HID) { b1_lds[u] = b1[u]; w2_lds[u] = W2[u]; }
    h_hist[31 * HP + u] = 0.0f;       // h(-1) in row 31
    float c = 0.0f;
    __syncthreads();

    float* outb = out + (size_t)b * T_LEN;
    const float* hrd = h_hist + 31 * HP;

    for (int tc = 0; tc < T_LEN / CHUNK; ++tc) {
        // ================= recurrence: 32 steps, NO barriers =================
        #pragma unroll 8
        for (int tt = 0; tt < CHUNK; ++tt) {
            const v4f* h4 = (const v4f*)hrd;        // broadcast b128 reads
            v2f aIF0, aIF1, aIF2, aIF3, aGO0, aGO1, aGO2, aGO3;
            {
                v4f hq = h4[0];
                aIF0 = pk_mul_lo(LO2(hq), wIF[0]);
                aIF1 = pk_mul_hi(LO2(hq), wIF[1]);
                aIF2 = pk_mul_lo(HI2(hq), wIF[2]);
                aIF3 = pk_mul_hi(HI2(hq), wIF[3]);
                aGO0 = pk_mul_lo(LO2(hq), wGO[0]);
                aGO1 = pk_mul_hi(LO2(hq), wGO[1]);
                aGO2 = pk_mul_lo(HI2(hq), wGO[2]);
                aGO3 = pk_mul_hi(HI2(hq), wGO[3]);
            }
            #pragma unroll
            for (int m = 1; m < 16; ++m) {
                v4f hq = h4[m];
                aIF0 = pk_fma_lo(LO2(hq), wIF[4 * m + 0], aIF0);
                aIF1 = pk_fma_hi(LO2(hq), wIF[4 * m + 1], aIF1);
                aIF2 = pk_fma_lo(HI2(hq), wIF[4 * m + 2], aIF2);
                aIF3 = pk_fma_hi(HI2(hq), wIF[4 * m + 3], aIF3);
                aGO0 = pk_fma_lo(LO2(hq), wGO[4 * m + 0], aGO0);
                aGO1 = pk_fma_hi(LO2(hq), wGO[4 * m + 1], aGO1);
                aGO2 = pk_fma_lo(HI2(hq), wGO[4 * m + 2], aGO2);
                aGO3 = pk_fma_hi(HI2(hq), wGO[4 * m + 3], aGO3);
            }
            float xv = x_lds[tc * CHUNK + tt];
            v2f xv2 = (v2f){xv, xv};
            v2f totIF = pk_add(pk_add(aIF0, aIF1), pk_add(aIF2, aIF3));
            v2f totGO = pk_add(pk_add(aGO0, aGO1), pk_add(aGO2, aGO3));
            totIF = pk_add(totIF, pk_fma(xv2, wihIF, biasIF));
            totGO = pk_add(totGO, pk_fma(xv2, wihGO, biasGO));

            float gi = fast_sigmoid(totIF.x);
            float gf = fast_sigmoid(totIF.y);
            float gg = fast_tanh(totGO.x);
            float go = fast_sigmoid(totGO.y);
            c = fmaf(gf, c, gi * gg);
            float hn = go * fast_tanh(c);

            float* hwr = h_hist + tt * HP;
            hwr[u] = hn;                    // t-major (next-step broadcast reads)
            h_T[u * HTP + tt] = hn;         // u-major (MLP reads)
            hrd = hwr;                      // intra-wave: lgkmcnt orders write->read
        }
        __syncthreads();   // single wave: cheap; fences h_T for the MLP phase

        // ================= fused MLP head for this chunk =================
        {
            const int tb = tc * CHUNK;
            const int tq = u & 7;           // t-quad 0..7  (t = 4tq..4tq+3)
            const int jq = u >> 3;          // j-quint 0..7 (j = 5jq..5jq+4)
            const int jb = 5 * jq;
            const float* w1base = w1_lds + jb * W1P;
            const float* htb = h_T + 4 * tq;

            v2f z0[5], z1[5];               // [j] x t-pairs {0,1} / {2,3}
            #pragma unroll
            for (int m = 0; m < 5; ++m) { z0[m] = (v2f){0.f, 0.f}; z1[m] = (v2f){0.f, 0.f}; }

            #pragma unroll
            for (int s = 0; s < 8; ++s) {   // 8 k per section, W1 hoisted as v2f PAIRS
                v2f wp[5][4];
                #pragma unroll
                for (int m = 0; m < 5; ++m) {
                    #pragma unroll
                    for (int p = 0; p < 4; ++p)
                        wp[m][p] = *(const v2f*)(w1base + m * W1P + 8 * s + 2 * p);
                }
                #pragma unroll
                for (int kk = 0; kk < 8; ++kk) {
                    const float* hr = htb + (8 * s + kk) * HTP;
                    v2f hlo = *(const v2f*)(hr);        // t {4tq, 4tq+1}
                    v2f hhi = *(const v2f*)(hr + 2);    // t {4tq+2, 4tq+3}
                    #pragma unroll
                    for (int m = 0; m < 5; ++m) {
                        if (kk & 1) {
                            z0[m] = pk_fma_whi(hlo, wp[m][kk >> 1], z0[m]);
                            z1[m] = pk_fma_whi(hhi, wp[m][kk >> 1], z1[m]);
                        } else {
                            z0[m] = pk_fma_wlo(hlo, wp[m][kk >> 1], z0[m]);
                            z1[m] = pk_fma_wlo(hhi, wp[m][kk >> 1], z1[m]);
                        }
                    }
                }
            }
            // x term (k = 64 column of W1; load {w64,pad} pair, broadcast lo)
            v4f xq = *(const v4f*)(x_lds + tb + 4 * tq);
            #pragma unroll
            for (int m = 0; m < 5; ++m) {
                v2f wx = *(const v2f*)(w1base + m * W1P + 64);
                z0[m] = pk_fma_wlo(LO2(xq), wx, z0[m]);
                z1[m] = pk_fma_wlo(HI2(xq), wx, z1[m]);
            }
            // sigmoid + W2 partials
            float y0 = 0.f, y1 = 0.f, y2 = 0.f, y3 = 0.f;
            #pragma unroll
            for (int m = 0; m < 5; ++m) {
                float bm = b1_lds[jb + m], w2m = w2_lds[jb + m];
                y0 = fmaf(fast_sigmoid(z0[m].x + bm), w2m, y0);
                y1 = fmaf(fast_sigmoid(z0[m].y + bm), w2m, y1);
                y2 = fmaf(fast_sigmoid(z1[m].x + bm), w2m, y2);
                y3 = fmaf(fast_sigmoid(z1[m].y + bm), w2m, y3);
            }
            red_lds[(4 * tq + 0) * RP + jq] = y0;
            red_lds[(4 * tq + 1) * RP + jq] = y1;
            red_lds[(4 * tq + 2) * RP + jq] = y2;
            red_lds[(4 * tq + 3) * RP + jq] = y3;
            __syncthreads();
            if (u < CHUNK) {
                float y = b2v;
                #pragma unroll
                for (int j2 = 0; j2 < 8; ++j2) y += red_lds[u * RP + j2];
                outb[tb + u] = y;
            }
            __syncthreads();   // before next chunk overwrites h_T / red_lds
        }
    }
}

extern "C" void kernel_launch(void* const* d_in, const int* in_sizes, int n_in,
                              void* d_out, int out_size, void* d_ws, size_t ws_size,
                              hipStream_t stream) {
    const float* inputs = (const float*)d_in[0];
    const float* W_ih   = (const float*)d_in[1];
    const float* W_hh   = (const float*)d_in[2];
    const float* b_ih   = (const float*)d_in[3];
    const float* b_hh   = (const float*)d_in[4];
    const float* W1     = (const float*)d_in[5];
    const float* b1     = (const float*)d_in[6];
    const float* W2     = (const float*)d_in[7];
    const float* b2     = (const float*)d_in[8];
    float* out = (float*)d_out;

    lstm_mlp_kernel<<<dim3(256), dim3(64), 0, stream>>>(
        inputs, W_ih, W_hh, b_ih, b_hh, W1, b1, W2, b2, out);
}

// Round 9
// 1812.141 us; speedup vs baseline: 3.5526x; 3.5526x over previous
//
#include <hip/hip_runtime.h>

#define T_LEN  4096
#define CHUNK  32
#define MLP_HID 40
#define HROW   72    // h16 row pitch in f16 (144B: 16B-aligned, MLP stride ok)
#define HROWU  36    // same pitch in uints
#define W1PU   36    // w1h row pitch in half2/uint units (144B aligned)
#define RP     9     // red_lds pitch (floats)

typedef float  v2f __attribute__((ext_vector_type(2)));
typedef float  v4f __attribute__((ext_vector_type(4)));
typedef _Float16 h2 __attribute__((ext_vector_type(2)));

__device__ __forceinline__ float fdot2(h2 a, h2 b, float c) {
#if defined(__has_builtin) && __has_builtin(__builtin_amdgcn_fdot2)
    return __builtin_amdgcn_fdot2(a, b, c, false);
#else
    float d;
    asm("v_dot2_f32_f16 %0, %1, %2, %3" : "=v"(d) : "v"(a), "v"(b), "v"(c));
    return d;
#endif
}
__device__ __forceinline__ h2 pack16(float a, float b) {
    return (h2){(_Float16)a, (_Float16)b};
}
__device__ __forceinline__ float fast_sigmoid(float x) {
    float e = __builtin_amdgcn_exp2f(x * -1.4426950408889634f);
    return __builtin_amdgcn_rcpf(1.0f + e);
}
__device__ __forceinline__ float fast_tanh(float x) {
    float e = __builtin_amdgcn_exp2f(x * 2.8853900817779268f);
    return 1.0f - 2.0f * __builtin_amdgcn_rcpf(1.0f + e);
}

__global__ __launch_bounds__(64, 1)
void lstm_mlp_kernel(const float* __restrict__ inputs,
                     const float* __restrict__ W_ih,
                     const float* __restrict__ W_hh,
                     const float* __restrict__ b_ih,
                     const float* __restrict__ b_hh,
                     const float* __restrict__ W1,
                     const float* __restrict__ b1,
                     const float* __restrict__ W2,
                     const float* __restrict__ b2,
                     float* __restrict__ out)
{
    __shared__ __align__(16) float    x_lds[T_LEN];          // 16 KB input row (fp32)
    __shared__ __align__(16) _Float16 h16_lds[CHUNK * HROW]; // h history, f16
    __shared__ __align__(16) h2       w1h_lds[MLP_HID * W1PU]; // W1 f16 k-pairs
    __shared__ float w1x_lds[MLP_HID];                       // W1[:,64] (x col, fp32)
    __shared__ float b1_lds[MLP_HID];
    __shared__ float w2_lds[MLP_HID];
    __shared__ float red_lds[CHUNK * RP];

    const int u = threadIdx.x;        // lane = hidden unit (64 lanes, 1 wave)
    const int b = blockIdx.x;

    // ---- prologue: stage x row (fp32, exact) ----
    const float4* in4 = (const float4*)(inputs + (size_t)b * T_LEN);
    float4* x4 = (float4*)x_lds;
    #pragma unroll
    for (int r = 0; r < 16; ++r) x4[u + 64 * r] = in4[u + 64 * r];

    // W_hh rows i,f,g,o of unit u -> f16 k-pairs in registers: 128 half2 = 128 VGPR
    h2 wd[4][32];
    #pragma unroll
    for (int g = 0; g < 4; ++g) {
        const v4f* p = (const v4f*)(W_hh + (g * 64 + u) * 64);
        #pragma unroll
        for (int m = 0; m < 16; ++m) {
            v4f t = p[m];
            wd[g][2 * m]     = pack16(t.x, t.y);
            wd[g][2 * m + 1] = pack16(t.z, t.w);
        }
    }
    const float wih0 = W_ih[u],       wih1 = W_ih[64 + u];
    const float wih2 = W_ih[128 + u], wih3 = W_ih[192 + u];
    const float bi0 = b_ih[u] + b_hh[u];
    const float bi1 = b_ih[64 + u] + b_hh[64 + u];
    const float bi2 = b_ih[128 + u] + b_hh[128 + u];
    const float bi3 = b_ih[192 + u] + b_hh[192 + u];
    const float b2v = b2[0];

    // W1 -> f16 pairs in LDS (k pairs 0..31), x-column/b1/w2 fp32
    for (int p = u; p < MLP_HID * 32; p += 64) {
        int j = p >> 5, kk = p & 31;
        w1h_lds[j * W1PU + kk] = pack16(W1[j * 65 + 2 * kk], W1[j * 65 + 2 * kk + 1]);
    }
    if (u < MLP_HID) {
        w1x_lds[u] = W1[u * 65 + 64];
        b1_lds[u]  = b1[u];
        w2_lds[u]  = W2[u];
    }
    h16_lds[31 * HROW + u] = (_Float16)0.0f;   // h(-1) in row 31
    float c = 0.0f;
    __syncthreads();

    float* outb = out + (size_t)b * T_LEN;
    const uint4* h16u = (const uint4*)h16_lds;  // row r at uint4 index r*HROWU/4

    for (int tc = 0; tc < T_LEN / CHUNK; ++tc) {
        // ============ recurrence: 32 steps, single wave, NO barriers ============
        #pragma unroll 4
        for (int tt = 0; tt < CHUNK; ++tt) {
            const int rp = (tt + CHUNK - 1) & (CHUNK - 1);     // prev-h row
            const uint4* hr = h16u + rp * (HROWU / 4);          // 8 x b128 broadcast

            float a0a = 0.f, a0b = 0.f, a1a = 0.f, a1b = 0.f;
            float a2a = 0.f, a2b = 0.f, a3a = 0.f, a3b = 0.f;
            #pragma unroll
            for (int m = 0; m < 8; ++m) {                       // 8 f16 per read
                uint4 hq = hr[m];
                h2 p0 = __builtin_bit_cast(h2, hq.x);
                h2 p1 = __builtin_bit_cast(h2, hq.y);
                h2 p2 = __builtin_bit_cast(h2, hq.z);
                h2 p3 = __builtin_bit_cast(h2, hq.w);
                a0a = fdot2(p0, wd[0][4 * m + 0], a0a);
                a0b = fdot2(p1, wd[0][4 * m + 1], a0b);
                a1a = fdot2(p0, wd[1][4 * m + 0], a1a);
                a1b = fdot2(p1, wd[1][4 * m + 1], a1b);
                a2a = fdot2(p0, wd[2][4 * m + 0], a2a);
                a2b = fdot2(p1, wd[2][4 * m + 1], a2b);
                a3a = fdot2(p0, wd[3][4 * m + 0], a3a);
                a3b = fdot2(p1, wd[3][4 * m + 1], a3b);
                a0a = fdot2(p2, wd[0][4 * m + 2], a0a);
                a0b = fdot2(p3, wd[0][4 * m + 3], a0b);
                a1a = fdot2(p2, wd[1][4 * m + 2], a1a);
                a1b = fdot2(p3, wd[1][4 * m + 3], a1b);
                a2a = fdot2(p2, wd[2][4 * m + 2], a2a);
                a2b = fdot2(p3, wd[2][4 * m + 3], a2b);
                a3a = fdot2(p2, wd[3][4 * m + 2], a3a);
                a3b = fdot2(p3, wd[3][4 * m + 3], a3b);
            }
            float xv = x_lds[tc * CHUNK + tt];
            float pre0 = (a0a + a0b) + fmaf(xv, wih0, bi0);
            float pre1 = (a1a + a1b) + fmaf(xv, wih1, bi1);
            float pre2 = (a2a + a2b) + fmaf(xv, wih2, bi2);
            float pre3 = (a3a + a3b) + fmaf(xv, wih3, bi3);

            float gi = fast_sigmoid(pre0);
            float gf = fast_sigmoid(pre1);
            float gg = fast_tanh(pre2);
            float go = fast_sigmoid(pre3);
            c = fmaf(gf, c, gi * gg);
            float hn = go * fast_tanh(c);

            h16_lds[tt * HROW + u] = (_Float16)hn;   // b16 write; lgkmcnt orders
        }
        __syncthreads();   // single wave: cheap; fences h16 for the MLP phase

        // ================= fused MLP head for this chunk =================
        {
            const int tb = tc * CHUNK;
            const int tq = u & 7;           // t-quad 0..7  (t = 4tq..4tq+3)
            const int jq = u >> 3;          // j-quint 0..7 (j = 5jq..5jq+4)
            const int jb = 5 * jq;
            const uint4* w1q = (const uint4*)w1h_lds;   // row j at j*W1PU/4

            float z[5][4];
            #pragma unroll
            for (int m = 0; m < 5; ++m)
                #pragma unroll
                for (int i = 0; i < 4; ++i) z[m][i] = 0.f;

            #pragma unroll
            for (int s = 0; s < 8; ++s) {   // 8 k-values (4 pairs) per section
                uint4 wv[5];
                #pragma unroll
                for (int m = 0; m < 5; ++m)
                    wv[m] = w1q[(jb + m) * (W1PU / 4) + s];
                uint4 hv[4];
                #pragma unroll
                for (int i = 0; i < 4; ++i)
                    hv[i] = h16u[(4 * tq + i) * (HROWU / 4) + s];
                #pragma unroll
                for (int m = 0; m < 5; ++m) {
                    #pragma unroll
                    for (int i = 0; i < 4; ++i) {
                        z[m][i] = fdot2(__builtin_bit_cast(h2, hv[i].x),
                                        __builtin_bit_cast(h2, wv[m].x), z[m][i]);
                        z[m][i] = fdot2(__builtin_bit_cast(h2, hv[i].y),
                                        __builtin_bit_cast(h2, wv[m].y), z[m][i]);
                        z[m][i] = fdot2(__builtin_bit_cast(h2, hv[i].z),
                                        __builtin_bit_cast(h2, wv[m].z), z[m][i]);
                        z[m][i] = fdot2(__builtin_bit_cast(h2, hv[i].w),
                                        __builtin_bit_cast(h2, wv[m].w), z[m][i]);
                    }
                }
            }
            // x column (fp32) + sigmoid + W2 partials
            v4f xq = *(const v4f*)(x_lds + tb + 4 * tq);
            float y0 = 0.f, y1 = 0.f, y2 = 0.f, y3 = 0.f;
            #pragma unroll
            for (int m = 0; m < 5; ++m) {
                float wx = w1x_lds[jb + m];
                float bm = b1_lds[jb + m];
                float w2m = w2_lds[jb + m];
                y0 = fmaf(fast_sigmoid(fmaf(xq[0], wx, z[m][0]) + bm), w2m, y0);
                y1 = fmaf(fast_sigmoid(fmaf(xq[1], wx, z[m][1]) + bm), w2m, y1);
                y2 = fmaf(fast_sigmoid(fmaf(xq[2], wx, z[m][2]) + bm), w2m, y2);
                y3 = fmaf(fast_sigmoid(fmaf(xq[3], wx, z[m][3]) + bm), w2m, y3);
            }
            red_lds[(4 * tq + 0) * RP + jq] = y0;
            red_lds[(4 * tq + 1) * RP + jq] = y1;
            red_lds[(4 * tq + 2) * RP + jq] = y2;
            red_lds[(4 * tq + 3) * RP + jq] = y3;
            __syncthreads();
            if (u < CHUNK) {
                float y = b2v;
                #pragma unroll
                for (int j2 = 0; j2 < 8; ++j2) y += red_lds[u * RP + j2];
                outb[tb + u] = y;
            }
            __syncthreads();   // before next chunk overwrites h16 / red_lds
        }
    }
}

extern "C" void kernel_launch(void* const* d_in, const int* in_sizes, int n_in,
                              void* d_out, int out_size, void* d_ws, size_t ws_size,
                              hipStream_t stream) {
    const float* inputs = (const float*)d_in[0];
    const float* W_ih   = (const float*)d_in[1];
    const float* W_hh   = (const float*)d_in[2];
    const float* b_ih   = (const float*)d_in[3];
    const float* b_hh   = (const float*)d_in[4];
    const float* W1     = (const float*)d_in[5];
    const float* b1     = (const float*)d_in[6];
    const float* W2     = (const float*)d_in[7];
    const float* b2     = (const float*)d_in[8];
    float* out = (float*)d_out;

    lstm_mlp_kernel<<<dim3(256), dim3(64), 0, stream>>>(
        inputs, W_ih, W_hh, b_ih, b_hh, W1, b1, W2, b2, out);
}

// Round 10
// 1562.568 us; speedup vs baseline: 4.1200x; 1.1597x over previous
//
#include <hip/hip_runtime.h>

#define T_LEN  4096
#define CHUNK  32
#define MLP_HID 40
#define HROW16 80    // h16 row pitch in f16 (160B): bank-safe for MLP strided reads
#define HRU4   10    // same pitch in uint4
#define W1H2P  40    // W1 f16 row pitch in h2 (160B)
#define W1U4   10    // same pitch in uint4
#define ZP     41    // z_lds row pitch (floats)

typedef float  v4f __attribute__((ext_vector_type(4)));
typedef _Float16 h2 __attribute__((ext_vector_type(2)));

__device__ __forceinline__ float fdot2(h2 a, h2 b, float c) {
    return __builtin_amdgcn_fdot2(a, b, c, false);
}
__device__ __forceinline__ h2 pack16(float a, float b) {
    return (h2){(_Float16)a, (_Float16)b};
}
__device__ __forceinline__ h2 bch2(unsigned int x) {
    return __builtin_bit_cast(h2, x);
}
// cross-lane via builtins ONLY (raw DPP asm caused round-3 numerics failure)
__device__ __forceinline__ float dpp_x1(float v) {   // quad_perm [1,0,3,2]
    return __int_as_float(__builtin_amdgcn_update_dpp(
        0, __float_as_int(v), 0xB1, 0xF, 0xF, true));
}
__device__ __forceinline__ float dpp_x2(float v) {   // quad_perm [2,3,0,1]
    return __int_as_float(__builtin_amdgcn_update_dpp(
        0, __float_as_int(v), 0x4E, 0xF, 0xF, true));
}
__device__ __forceinline__ float fast_sigmoid(float x) {
    float e = __builtin_amdgcn_exp2f(x * -1.4426950408889634f);
    return __builtin_amdgcn_rcpf(1.0f + e);
}

__global__ __launch_bounds__(256, 1)
void lstm_mlp_kernel(const float* __restrict__ inputs,
                     const float* __restrict__ W_ih,
                     const float* __restrict__ W_hh,
                     const float* __restrict__ b_ih,
                     const float* __restrict__ b_hh,
                     const float* __restrict__ W1,
                     const float* __restrict__ b1,
                     const float* __restrict__ W2,
                     const float* __restrict__ b2,
                     float* __restrict__ out)
{
    __shared__ __align__(16) float    x_lds[T_LEN];            // fp32 input row
    __shared__ __align__(16) _Float16 h16_lds[CHUNK * HROW16]; // f16 h history
    __shared__ __align__(16) h2       w1h_lds[MLP_HID * W1H2P];// W1 f16 k-pairs
    __shared__ float w1x_lds[MLP_HID];                         // W1[:,64] fp32
    __shared__ float b1_lds[MLP_HID];
    __shared__ float w2_lds[MLP_HID];
    __shared__ float z_lds[CHUNK * ZP];

    const int tid = threadIdx.x;
    const int b   = blockIdx.x;
    const int w   = tid >> 6;        // wave 0..3
    const int l   = tid & 63;
    const int r   = l >> 2;          // unit-in-wave 0..15
    const int q   = l & 3;           // quad role: gate type AND K-quarter
    const int u   = 16 * w + r;      // hidden unit owned by this quad
    const bool q1 = (q & 1) != 0;
    const bool q2 = (q & 2) != 0;
    const bool wlane = (q == 1);

    // ---- prologue: stage x row ----
    const float4* in4 = (const float4*)(inputs + (size_t)b * T_LEN);
    float4* x4 = (float4*)x_lds;
    #pragma unroll
    for (int rr2 = 0; rr2 < 4; ++rr2) x4[tid + 256 * rr2] = in4[tid + 256 * rr2];

    // W_hh[j*64+u][16q..16q+16) -> f16 pairs: 4 gates x 8 h2 = 32 VGPR
    h2 wd[4][8];
    #pragma unroll
    for (int j = 0; j < 4; ++j) {
        const v4f* p = (const v4f*)(W_hh + (j * 64 + u) * 64 + 16 * q);
        #pragma unroll
        for (int m = 0; m < 4; ++m) {
            v4f t = p[m];
            wd[j][2 * m]     = pack16(t.x, t.y);
            wd[j][2 * m + 1] = pack16(t.z, t.w);
        }
    }
    // own gate (type q, unit u)
    const int   gown = q * 64 + u;
    const float wq   = W_ih[gown];
    const float bq   = b_ih[gown] + b_hh[gown];
    const float m_c  = (q == 2) ?  2.8853900817779268f : -1.4426950408889634f;
    const float a_c  = (q == 2) ? -2.0f : 1.0f;
    const float d_c  = (q == 2) ?  1.0f : 0.0f;
    const float b2v  = b2[0];

    // W1 -> f16 pairs in LDS; x-column / b1 / W2 stay fp32
    for (int p = tid; p < MLP_HID * 32; p += 256) {
        int j = p >> 5, kk = p & 31;
        w1h_lds[j * W1H2P + kk] = pack16(W1[j * 65 + 2 * kk], W1[j * 65 + 2 * kk + 1]);
    }
    if (tid < MLP_HID) {
        w1x_lds[tid] = W1[tid * 65 + 64];
        b1_lds[tid]  = b1[tid];
        w2_lds[tid]  = W2[tid];
    }
    if (tid < 64) h16_lds[31 * HROW16 + tid] = (_Float16)0.0f;  // h(-1) row 31
    float c = 0.0f;
    __syncthreads();

    float* outb = out + (size_t)b * T_LEN;
    const uint4* h16u4 = (const uint4*)h16_lds;

    for (int tc = 0; tc < T_LEN / CHUNK; ++tc) {
        const float* xcb = x_lds + tc * CHUNK;

        #pragma unroll
        for (int tt = 0; tt < CHUNK; ++tt) {
            const int rp = (tt + CHUNK - 1) & (CHUNK - 1);   // compile-time row
            const uint4* hr = h16u4 + rp * HRU4 + 2 * q;     // lane's 32B K-slice
            uint4 hqa = hr[0], hqb = hr[1];
            h2 p0 = bch2(hqa.x), p1 = bch2(hqa.y), p2 = bch2(hqa.z), p3 = bch2(hqa.w);
            h2 p4 = bch2(hqb.x), p5 = bch2(hqb.y), p6 = bch2(hqb.z), p7 = bch2(hqb.w);
            float xv = xcb[tt];

            // ---- 4 gate partials over 16-K slice: 32 dot2 ----
            float acc[4];
            #pragma unroll
            for (int j = 0; j < 4; ++j) {
                float aa = fdot2(p0, wd[j][0], 0.0f);
                float ab = fdot2(p1, wd[j][1], 0.0f);
                aa = fdot2(p2, wd[j][2], aa);
                ab = fdot2(p3, wd[j][3], ab);
                aa = fdot2(p4, wd[j][4], aa);
                ab = fdot2(p5, wd[j][5], ab);
                aa = fdot2(p6, wd[j][6], aa);
                ab = fdot2(p7, wd[j][7], ab);
                acc[j] = aa + ab;
            }
            // ---- butterfly stage 1, per-lane select, stage 2 (round-5 verbatim) ----
            #pragma unroll
            for (int j = 0; j < 4; ++j) acc[j] += dpp_x1(acc[j]);
            float t0 = q1 ? acc[1] : acc[0];
            float t1 = q1 ? acc[3] : acc[2];
            float s_own  = q2 ? t1 : t0;
            float s_part = q2 ? t0 : t1;
            float tot = s_own + dpp_x2(s_part);    // full own-gate sum

            // single activation per lane
            float pre = tot + fmaf(xv, wq, bq);
            float act = fmaf(a_c, __builtin_amdgcn_rcpf(
                              1.0f + __builtin_amdgcn_exp2f(m_c * pre)), d_c);

            // quad exchange: f and i*g to all lanes (lane q==1 keeps o)
            float recv = dpp_x2(act);              // 0:g 1:o 2:i 3:f
            float p    = act * recv;               // lanes 0,2: i*g
            float e0 = q2 ? recv : act;
            float e  = q1 ? e0 : p;
            float rr = dpp_x1(e);
            float fv = q1 ? e : rr;
            float ig = q1 ? rr : e;
            c = fmaf(fv, c, ig);
            float th = fmaf(-2.0f, __builtin_amdgcn_rcpf(
                             1.0f + __builtin_amdgcn_exp2f(2.8853900817779268f * c)), 1.0f);
            float ov = q2 ? act : recv;            // o (valid on lane q==1)
            float hn = ov * th;
            if (wlane) h16_lds[tt * HROW16 + u] = (_Float16)hn;
            __syncthreads();                       // the ONLY per-step barrier
        }

        // ---- fused MLP head for this chunk (f16 dot2) ----
        {
            int tbase = tc * CHUNK;
            int tl = tid >> 3, j0 = tid & 7;       // 32 t-rows x 8 j-lanes
            uint4 hh[8];
            const uint4* hrow = h16u4 + tl * HRU4;
            #pragma unroll
            for (int m = 0; m < 8; ++m) hh[m] = hrow[m];
            float xc = x_lds[tbase + tl];
            const uint4* w1u4 = (const uint4*)w1h_lds;
            #pragma unroll
            for (int jj = 0; jj < 5; ++jj) {
                int j = j0 + 8 * jj;
                const uint4* wrow = w1u4 + j * W1U4;
                float za = b1_lds[j], zb = 0.f;
                #pragma unroll
                for (int m = 0; m < 8; ++m) {
                    uint4 wv = wrow[m];
                    za = fdot2(bch2(hh[m].x), bch2(wv.x), za);
                    zb = fdot2(bch2(hh[m].y), bch2(wv.y), zb);
                    za = fdot2(bch2(hh[m].z), bch2(wv.z), za);
                    zb = fdot2(bch2(hh[m].w), bch2(wv.w), zb);
                }
                float zacc = (za + zb) + xc * w1x_lds[j];
                z_lds[tl * ZP + j] = fast_sigmoid(zacc);
            }
            __syncthreads();
            if (tid < CHUNK) {                     // 32 lanes reduce 40 z's
                float y = b2v;
                #pragma unroll
                for (int j = 0; j < MLP_HID; ++j)
                    y = fmaf(w2_lds[j], z_lds[tid * ZP + j], y);
                outb[tbase + tid] = y;
            }
            // next h write (row 0) is fenced by the mid-MLP barrier; hh/z
            // values already consumed — no trailing barrier needed.
        }
    }
}

extern "C" void kernel_launch(void* const* d_in, const int* in_sizes, int n_in,
                              void* d_out, int out_size, void* d_ws, size_t ws_size,
                              hipStream_t stream) {
    const float* inputs = (const float*)d_in[0];
    const float* W_ih   = (const float*)d_in[1];
    const float* W_hh   = (const float*)d_in[2];
    const float* b_ih   = (const float*)d_in[3];
    const float* b_hh   = (const float*)d_in[4];
    const float* W1     = (const float*)d_in[5];
    const float* b1     = (const float*)d_in[6];
    const float* W2     = (const float*)d_in[7];
    const float* b2     = (const float*)d_in[8];
    float* out = (float*)d_out;

    lstm_mlp_kernel<<<dim3(256), dim3(256), 0, stream>>>(
        inputs, W_ih, W_hh, b_ih, b_hh, W1, b1, W2, b2, out);
}